// Round 4
// baseline (889.235 us; speedup 1.0000x reference)
//
#include <hip/hip_runtime.h>

#define BB 64
#define SS 2048
#define FF 256
#define CC 32

typedef unsigned u32x2 __attribute__((ext_vector_type(2)));

// Two-result permlane swaps (builtin returns {vdst, vsrc} in distinct regs).
__device__ __forceinline__ void plswap16(int a_in, int& x, int& y) {
#if __has_builtin(__builtin_amdgcn_permlane16_swap)
    u32x2 r = __builtin_amdgcn_permlane16_swap((unsigned)a_in, (unsigned)a_in, false, false);
    x = (int)r[0]; y = (int)r[1];
#else
    int xx = a_in, yy;
    asm volatile("v_mov_b32 %0, %1" : "=v"(yy) : "v"(a_in));
    asm volatile("v_permlane16_swap_b32 %0, %1" : "+v"(xx), "+v"(yy));
    x = xx; y = yy;
#endif
}
__device__ __forceinline__ void plswap32(int a_in, int& x, int& y) {
#if __has_builtin(__builtin_amdgcn_permlane32_swap)
    u32x2 r = __builtin_amdgcn_permlane32_swap((unsigned)a_in, (unsigned)a_in, false, false);
    x = (int)r[0]; y = (int)r[1];
#else
    int xx = a_in, yy;
    asm volatile("v_mov_b32 %0, %1" : "=v"(yy) : "v"(a_in));
    asm volatile("v_permlane32_swap_b32 %0, %1" : "+v"(xx), "+v"(yy));
    x = xx; y = yy;
#endif
}

// ---------------------------------------------------------------------------
// Kernel 1: emissions GEMM — UNCHANGED (bit-exact; not the bottleneck).
// ---------------------------------------------------------------------------
__global__ __launch_bounds__(256) void emis_kernel(const float* __restrict__ X,
                                                   const float* __restrict__ W,
                                                   const float* __restrict__ bias,
                                                   float* __restrict__ em) {
    __shared__ __align__(16) float xs[64 * 260];
    __shared__ __align__(16) float wsh[32 * 260];
    const int tid = threadIdx.x;
    const long rowbase = (long)blockIdx.x * 64;

    const float4* Xg = (const float4*)(X + rowbase * FF);
#pragma unroll
    for (int i = 0; i < 16; ++i) {
        int idx = tid + i * 256;
        int r = idx >> 6, c4 = idx & 63;
        *(float4*)&xs[r * 260 + c4 * 4] = Xg[idx];
    }
    const float4* Wg = (const float4*)W;
#pragma unroll
    for (int i = 0; i < 8; ++i) {
        int idx = tid + i * 256;
        int r = idx >> 6, c4 = idx & 63;
        *(float4*)&wsh[r * 260 + c4 * 4] = Wg[idx];
    }
    __syncthreads();

    const int rp = tid >> 3;
    const int cg = (tid & 7) * 4;
    const int r0 = rp * 2, r1 = rp * 2 + 1;
    float acc0[4] = {0.f, 0.f, 0.f, 0.f};
    float acc1[4] = {0.f, 0.f, 0.f, 0.f};

#pragma unroll 4
    for (int k = 0; k < 256; k += 4) {
        float4 xa = *(const float4*)&xs[r0 * 260 + k];
        float4 xb = *(const float4*)&xs[r1 * 260 + k];
#pragma unroll
        for (int jj = 0; jj < 4; ++jj) {
            float4 w = *(const float4*)&wsh[(cg + jj) * 260 + k];
            acc0[jj] = fmaf(xa.x, w.x, acc0[jj]);
            acc0[jj] = fmaf(xa.y, w.y, acc0[jj]);
            acc0[jj] = fmaf(xa.z, w.z, acc0[jj]);
            acc0[jj] = fmaf(xa.w, w.w, acc0[jj]);
            acc1[jj] = fmaf(xb.x, w.x, acc1[jj]);
            acc1[jj] = fmaf(xb.y, w.y, acc1[jj]);
            acc1[jj] = fmaf(xb.z, w.z, acc1[jj]);
            acc1[jj] = fmaf(xb.w, w.w, acc1[jj]);
        }
    }
#pragma unroll
    for (int jj = 0; jj < 4; ++jj) {
        float bj = bias[cg + jj];
        em[(rowbase + r0) * CC + cg + jj] = acc0[jj] + bj;
        em[(rowbase + r1) * CC + cg + jj] = acc1[jj] + bj;
    }
}

// ---------------------------------------------------------------------------
// Kernel 2: forward Viterbi scan.
//   * 8 waves/block (8 batches), 2 waves/SIMD -> TLP fills dependency bubbles.
//   * Emissions staged 32 steps at a time through per-wave double-buffered LDS
//     (loads issued one block ahead; ds_write just before use; per-step
//     conflict-free ds_read_b32). Removes the ~600 cyc/step load stall of r3.
//   * Step arithmetic identical to round 3 (bit-exact, absmax 0.0).
// ---------------------------------------------------------------------------
#define ROT1(d, s, K) d = __builtin_amdgcn_update_dpp(s, s, 0x120 + K, 0xF, 0xF, false)
#define ROTALL(arr, s) \
    arr[0] = s;        \
    ROT1(arr[1], s, 1);  ROT1(arr[2], s, 2);  ROT1(arr[3], s, 3);  \
    ROT1(arr[4], s, 4);  ROT1(arr[5], s, 5);  ROT1(arr[6], s, 6);  \
    ROT1(arr[7], s, 7);  ROT1(arr[8], s, 8);  ROT1(arr[9], s, 9);  \
    ROT1(arr[10], s, 10); ROT1(arr[11], s, 11); ROT1(arr[12], s, 12); \
    ROT1(arr[13], s, 13); ROT1(arr[14], s, 14); ROT1(arr[15], s, 15)

__device__ __forceinline__ int imin_(int a, int b) { return a < b ? a : b; }
__device__ __forceinline__ int imin3_(int a, int b, int c) { return imin_(imin_(a, b), c); }
__device__ __forceinline__ float fmax3_(float a, float b, float c) { return fmaxf(fmaxf(a, b), c); }

__global__ __launch_bounds__(512) void viterbi_fwd(const float* __restrict__ em,
                                                   const float* __restrict__ T,
                                                   const float* __restrict__ startT,
                                                   const float* __restrict__ endT,
                                                   unsigned* __restrict__ bp,
                                                   float* __restrict__ out) {
    __shared__ float ebuf[8][2][1024];     // per-wave double buffer: 2 x 32 steps x 32 states
    const int tid = threadIdx.x;
    const int w = tid >> 6;                // wave 0..7
    const int l = tid & 63;
    const int b = blockIdx.x * 8 + w;      // batch
    const int j = l & 31;
    const int h = l >> 5;

    // probe permlane16_swap orientation
    int p0, p1;
    plswap16(j, p0, p1);
    const bool c16 = (((p0 >> 4) & 1) == h);
    const int pm = c16 ? p0 : p1;
    int mk[16];
    ROTALL(mk, pm);                        // mk[k] = abs alpha-index delivered by rot k
    // probe permlane32_swap orientation
    int q0, q1;
    plswap32(l, q0, q1);
    const bool pick0 = (q0 == (l ^ 32));

    float Ti[16];
#pragma unroll
    for (int k = 0; k < 16; ++k) Ti[k] = T[mk[k] * CC + j];

    const float* eb = em + (long)b * SS * CC;
    const float4* ebv = (const float4*)eb;

    // block 0 (t=0..31): load + stage directly
    float4 st[4];
#pragma unroll
    for (int v = 0; v < 4; ++v) st[v] = ebv[v * 64 + l];
#pragma unroll
    for (int v = 0; v < 4; ++v) *(float4*)&ebuf[w][0][v * 256 + l * 4] = st[v];
    // issue block 1 loads (consumed ~1 block of compute later)
#pragma unroll
    for (int v = 0; v < 4; ++v) st[v] = ebv[256 + v * 64 + l];

    float a = startT[j] + ebuf[w][0][j];   // t = 0
    unsigned bpw = 0;

    auto step = [&](float e, int t, int phase) {
        int x, y;
        plswap16(__float_as_int(a), x, y);
        int base = c16 ? x : y;
        int rot[16];
        ROTALL(rot, base);
        float s[16];
#pragma unroll
        for (int k = 0; k < 16; ++k) s[k] = __int_as_float(rot[k]) + Ti[k];

        // exact max (tree shape can't change result)
        float m0 = fmax3_(s[0], s[1], s[2]);
        float m1 = fmax3_(s[3], s[4], s[5]);
        float m2 = fmax3_(s[6], s[7], s[8]);
        float m3 = fmax3_(s[9], s[10], s[11]);
        float m4 = fmax3_(s[12], s[13], s[14]);
        float mv = fmaxf(fmax3_(m0, m1, m2), fmax3_(m3, m4, s[15]));

        // min index among maxes (== jnp.argmax first-occurrence)
        int c0 = (s[0] == mv) ? mk[0] : 63,   c1 = (s[1] == mv) ? mk[1] : 63;
        int c2 = (s[2] == mv) ? mk[2] : 63,   c3 = (s[3] == mv) ? mk[3] : 63;
        int c4 = (s[4] == mv) ? mk[4] : 63,   c5 = (s[5] == mv) ? mk[5] : 63;
        int c6 = (s[6] == mv) ? mk[6] : 63,   c7 = (s[7] == mv) ? mk[7] : 63;
        int c8 = (s[8] == mv) ? mk[8] : 63,   c9 = (s[9] == mv) ? mk[9] : 63;
        int c10 = (s[10] == mv) ? mk[10] : 63, c11 = (s[11] == mv) ? mk[11] : 63;
        int c12 = (s[12] == mv) ? mk[12] : 63, c13 = (s[13] == mv) ? mk[13] : 63;
        int c14 = (s[14] == mv) ? mk[14] : 63, c15 = (s[15] == mv) ? mk[15] : 63;
        int e0 = imin3_(c0, c1, c2), e1 = imin3_(c3, c4, c5);
        int e2 = imin3_(c6, c7, c8), e3 = imin3_(c9, c10, c11);
        int e4 = imin3_(c12, c13, c14);
        int mi = imin_(imin3_(e0, e1, e2), imin3_(e3, e4, c15));

        // cross-half combine
        int xm, ym;
        plswap32(__float_as_int(mv), xm, ym);
        float ov = __int_as_float(pick0 ? xm : ym);
        int xi, yi;
        plswap32(mi, xi, yi);
        int omi = pick0 ? xi : yi;
        bool take = (ov > mv) || (ov == mv && omi < mi);
        float wv = take ? ov : mv;
        int wi = take ? omi : mi;

        a = wv + e;

        bpw |= (unsigned)wi << (phase * 8);
        if (phase == 3) {
            int kk = t - 1;
            if (h == 0) bp[((unsigned)(kk >> 2) * BB + b) * CC + j] = bpw;
            bpw = 0;
        }
    };

    // block 0: steps t = 1..31
    {
        const float* buf = &ebuf[w][0][0];
#pragma unroll
        for (int u = 1; u < 16; ++u) step(buf[u * 32 + j], u, (u - 1) & 3);
#pragma unroll
        for (int u = 0; u < 16; ++u) step(buf[(16 + u) * 32 + j], 16 + u, (u + 3) & 3);
    }
    // blocks m = 1..63: write staged regs, issue next loads, 32 steps
    for (int m = 1; m < 64; ++m) {
        float* buf = &ebuf[w][m & 1][0];
#pragma unroll
        for (int v = 0; v < 4; ++v) *(float4*)&buf[v * 256 + l * 4] = st[v];
        if (m < 63) {
#pragma unroll
            for (int v = 0; v < 4; ++v) st[v] = ebv[(m + 1) * 256 + v * 64 + l];
        }
        const int tb = m << 5;
#pragma unroll
        for (int u = 0; u < 16; ++u) step(buf[u * 32 + j], tb + u, (u + 3) & 3);
#pragma unroll
        for (int u = 0; u < 16; ++u) step(buf[(16 + u) * 32 + j], tb + 16 + u, (u + 3) & 3);
    }

    // slot 511: phases 0..2 real + IDENTITY byte (uniform 64-step walks in bt)
    bpw |= (unsigned)j << 24;
    if (h == 0) bp[(511u * BB + b) * CC + j] = bpw;

    // final: best_score + last tag (tie -> lowest j)
    float v = a + endT[j];
    int idx = j;
#pragma unroll
    for (int d = 1; d <= 16; d <<= 1) {
        float ovv = __shfl_xor(v, d);
        int   oii = __shfl_xor(idx, d);
        bool c = (ovv > v) || (ovv == v && oii < idx);
        v = c ? ovv : v;
        idx = c ? oii : idx;
    }
    if (l == 0) {
        out[b] = v;
        out[BB + (long)b * SS + (SS - 1)] = (float)idx;
    }
}

// ---------------------------------------------------------------------------
// Backtrack as a function-composition scan over 32 chunks of 64 steps.
// UNCHANGED from round 3 (passed, ~40 us total).
// ---------------------------------------------------------------------------
__global__ __launch_bounds__(64) void bt_compose(const unsigned* __restrict__ bp,
                                                 unsigned char* __restrict__ G) {
    const int l = threadIdx.x, j = l & 31, hh = l >> 5;
    const int b = blockIdx.x >> 4;
    const int k = ((blockIdx.x & 15) << 1) | hh;
    const int lanebase = l & 32;

    unsigned sr[16];
#pragma unroll
    for (int p = 0; p < 16; ++p) sr[p] = bp[((unsigned)(16 * k + p) * BB + b) * CC + j];

    int g = j;
#pragma unroll
    for (int rel = 63; rel >= 0; --rel) {
        unsigned dw = (unsigned)__builtin_amdgcn_ds_bpermute((g | lanebase) << 2,
                                                             (int)sr[rel >> 2]);
        g = (int)((dw >> ((rel & 3) * 8)) & 31u);
    }
    G[(b * 32 + k) * 32 + j] = (unsigned char)g;
}

__global__ __launch_bounds__(64) void bt_scan(const unsigned char* __restrict__ G,
                                              const float* __restrict__ out,
                                              int* __restrict__ tagB) {
    __shared__ unsigned char Gs[64 * 32 * 32];
    const int l = threadIdx.x;
    const float4* Gg = (const float4*)G;
    float4* Gls = (float4*)Gs;
#pragma unroll
    for (int i = 0; i < 64; ++i) Gls[l + i * 64] = Gg[l + i * 64];
    __syncthreads();

    const int b = l;
    int cur = (int)out[BB + (long)b * SS + (SS - 1)];
    for (int k = 31; k >= 0; --k) {
        cur = Gs[(b * 32 + k) * 32 + cur];
        tagB[b * 32 + k] = cur;
    }
}

__global__ __launch_bounds__(64) void bt_emit(const unsigned* __restrict__ bp,
                                              const int* __restrict__ tagB,
                                              float* __restrict__ out) {
    const int l = threadIdx.x;
    const int b = blockIdx.x >> 5;
    const int k = blockIdx.x & 31;

    unsigned sr[16];
#pragma unroll
    for (int p = 0; p < 16; ++p) sr[p] = bp[((unsigned)(16 * k + p) * BB + b) * CC + (l & 31)];

    int start = (k == 31) ? (int)out[BB + (long)b * SS + (SS - 1)]
                          : tagB[b * 32 + k + 1];
    int g = start, cap = start;
#pragma unroll
    for (int rel = 63; rel >= 0; --rel) {
        unsigned dw = (unsigned)__builtin_amdgcn_ds_bpermute((g | (l & 32)) << 2,
                                                             (int)sr[rel >> 2]);
        g = (int)((dw >> ((rel & 3) * 8)) & 31u);
        cap = (l == rel) ? g : cap;
    }
    out[BB + (long)b * SS + k * 64 + l] = (float)cap;
}

// ---------------------------------------------------------------------------
extern "C" void kernel_launch(void* const* d_in, const int* in_sizes, int n_in,
                              void* d_out, int out_size, void* d_ws, size_t ws_size,
                              hipStream_t stream) {
    const float* X      = (const float*)d_in[0];
    const float* W      = (const float*)d_in[1];
    const float* bias   = (const float*)d_in[2];
    const float* T      = (const float*)d_in[3];
    const float* startT = (const float*)d_in[4];
    const float* endT   = (const float*)d_in[5];
    float* out = (float*)d_out;

    float*    em = (float*)d_ws;                                        // 16 MB
    unsigned* bp = (unsigned*)((char*)d_ws + (size_t)BB * SS * CC * 4); // 4 MB
    unsigned char* G    = (unsigned char*)d_ws;                         // reuse em head
    int*           tagB = (int*)((char*)d_ws + 65536);

    emis_kernel<<<(BB * SS) / 64, 256, 0, stream>>>(X, W, bias, em);
    viterbi_fwd<<<8, 512, 0, stream>>>(em, T, startT, endT, bp, out);
    bt_compose<<<BB * 16, 64, 0, stream>>>(bp, G);
    bt_scan<<<1, 64, 0, stream>>>(G, out, tagB);
    bt_emit<<<BB * 32, 64, 0, stream>>>(bp, tagB, out);
}

// Round 5
// 602.348 us; speedup vs baseline: 1.4763x; 1.4763x over previous
//
#include <hip/hip_runtime.h>

#define BB 64
#define SS 2048
#define FF 256
#define CC 32

typedef unsigned u32x2 __attribute__((ext_vector_type(2)));

// Two-result permlane swaps (builtin returns {vdst, vsrc} in distinct regs).
__device__ __forceinline__ void plswap16(int a_in, int& x, int& y) {
#if __has_builtin(__builtin_amdgcn_permlane16_swap)
    u32x2 r = __builtin_amdgcn_permlane16_swap((unsigned)a_in, (unsigned)a_in, false, false);
    x = (int)r[0]; y = (int)r[1];
#else
    int xx = a_in, yy;
    asm volatile("v_mov_b32 %0, %1" : "=v"(yy) : "v"(a_in));
    asm volatile("v_permlane16_swap_b32 %0, %1" : "+v"(xx), "+v"(yy));
    x = xx; y = yy;
#endif
}
__device__ __forceinline__ void plswap32(int a_in, int& x, int& y) {
#if __has_builtin(__builtin_amdgcn_permlane32_swap)
    u32x2 r = __builtin_amdgcn_permlane32_swap((unsigned)a_in, (unsigned)a_in, false, false);
    x = (int)r[0]; y = (int)r[1];
#else
    int xx = a_in, yy;
    asm volatile("v_mov_b32 %0, %1" : "=v"(yy) : "v"(a_in));
    asm volatile("v_permlane32_swap_b32 %0, %1" : "+v"(xx), "+v"(yy));
    x = xx; y = yy;
#endif
}

// ---------------------------------------------------------------------------
// Kernel 1: emissions GEMM — UNCHANGED (bit-exact; ~45 us, not the bottleneck).
// ---------------------------------------------------------------------------
__global__ __launch_bounds__(256) void emis_kernel(const float* __restrict__ X,
                                                   const float* __restrict__ W,
                                                   const float* __restrict__ bias,
                                                   float* __restrict__ em) {
    __shared__ __align__(16) float xs[64 * 260];
    __shared__ __align__(16) float wsh[32 * 260];
    const int tid = threadIdx.x;
    const long rowbase = (long)blockIdx.x * 64;

    const float4* Xg = (const float4*)(X + rowbase * FF);
#pragma unroll
    for (int i = 0; i < 16; ++i) {
        int idx = tid + i * 256;
        int r = idx >> 6, c4 = idx & 63;
        *(float4*)&xs[r * 260 + c4 * 4] = Xg[idx];
    }
    const float4* Wg = (const float4*)W;
#pragma unroll
    for (int i = 0; i < 8; ++i) {
        int idx = tid + i * 256;
        int r = idx >> 6, c4 = idx & 63;
        *(float4*)&wsh[r * 260 + c4 * 4] = Wg[idx];
    }
    __syncthreads();

    const int rp = tid >> 3;
    const int cg = (tid & 7) * 4;
    const int r0 = rp * 2, r1 = rp * 2 + 1;
    float acc0[4] = {0.f, 0.f, 0.f, 0.f};
    float acc1[4] = {0.f, 0.f, 0.f, 0.f};

#pragma unroll 4
    for (int k = 0; k < 256; k += 4) {
        float4 xa = *(const float4*)&xs[r0 * 260 + k];
        float4 xb = *(const float4*)&xs[r1 * 260 + k];
#pragma unroll
        for (int jj = 0; jj < 4; ++jj) {
            float4 w = *(const float4*)&wsh[(cg + jj) * 260 + k];
            acc0[jj] = fmaf(xa.x, w.x, acc0[jj]);
            acc0[jj] = fmaf(xa.y, w.y, acc0[jj]);
            acc0[jj] = fmaf(xa.z, w.z, acc0[jj]);
            acc0[jj] = fmaf(xa.w, w.w, acc0[jj]);
            acc1[jj] = fmaf(xb.x, w.x, acc1[jj]);
            acc1[jj] = fmaf(xb.y, w.y, acc1[jj]);
            acc1[jj] = fmaf(xb.z, w.z, acc1[jj]);
            acc1[jj] = fmaf(xb.w, w.w, acc1[jj]);
        }
    }
#pragma unroll
    for (int jj = 0; jj < 4; ++jj) {
        float bj = bias[cg + jj];
        em[(rowbase + r0) * CC + cg + jj] = acc0[jj] + bj;
        em[(rowbase + r1) * CC + cg + jj] = acc1[jj] + bj;
    }
}

// ---------------------------------------------------------------------------
// Kernel 2: forward Viterbi scan.
//   Grid: 64 blocks x 1 wave  -> 1 wave/SIMD on 64 CUs (own issue port).
//   Emissions: r4's proven LDS double-buffer staging (float4 loads issued one
//   32-step block ahead; ds_write forces the prefetch; per-step ds_read_b32,
//   conflict-free).
//   Step: trimmed argmax via bitmask+ffbl. gv = exact global max (fmax tree,
//   bit-identical to prior rounds); msk = OR((s[k]==gv)?Bk[k]:0);
//   full = msk | partner(msk); wi = ctz(full) = first index achieving max
//   == jnp.argmax. bp words identical across halves -> unconditional store.
// ---------------------------------------------------------------------------
#define ROT1(d, s, K) d = __builtin_amdgcn_update_dpp(s, s, 0x120 + K, 0xF, 0xF, false)
#define ROTALL(arr, s) \
    arr[0] = s;        \
    ROT1(arr[1], s, 1);  ROT1(arr[2], s, 2);  ROT1(arr[3], s, 3);  \
    ROT1(arr[4], s, 4);  ROT1(arr[5], s, 5);  ROT1(arr[6], s, 6);  \
    ROT1(arr[7], s, 7);  ROT1(arr[8], s, 8);  ROT1(arr[9], s, 9);  \
    ROT1(arr[10], s, 10); ROT1(arr[11], s, 11); ROT1(arr[12], s, 12); \
    ROT1(arr[13], s, 13); ROT1(arr[14], s, 14); ROT1(arr[15], s, 15)

__device__ __forceinline__ float fmax3_(float a, float b, float c) { return fmaxf(fmaxf(a, b), c); }

__global__ __launch_bounds__(64, 1) void viterbi_fwd(const float* __restrict__ em,
                                                     const float* __restrict__ T,
                                                     const float* __restrict__ startT,
                                                     const float* __restrict__ endT,
                                                     unsigned* __restrict__ bp,
                                                     float* __restrict__ out) {
    __shared__ float ebuf[2][1024];        // double buffer: 2 x 32 steps x 32 states
    const int l = threadIdx.x;
    const int b = blockIdx.x;
    const int j = l & 31;
    const int h = l >> 5;

    // probe permlane16_swap orientation
    int p0, p1;
    plswap16(j, p0, p1);
    const bool c16 = (((p0 >> 4) & 1) == h);
    const int pm = c16 ? p0 : p1;
    int mk[16];
    ROTALL(mk, pm);                        // mk[k] = abs alpha-index delivered by rot k
    // probe permlane32_swap orientation
    int q0, q1;
    plswap32(l, q0, q1);
    const bool pick0 = (q0 == (l ^ 32));

    float Ti[16];
    unsigned Bk[16];
#pragma unroll
    for (int k = 0; k < 16; ++k) {
        Ti[k] = T[mk[k] * CC + j];
        Bk[k] = 1u << mk[k];               // bit position = absolute predecessor index
    }

    const float* eb = em + (long)b * SS * CC;
    const float4* ebv = (const float4*)eb;

    // stage block 0 (t=0..31), then issue block-1 loads (consumed a block later)
    float4 st[4];
#pragma unroll
    for (int v = 0; v < 4; ++v) st[v] = ebv[v * 64 + l];
#pragma unroll
    for (int v = 0; v < 4; ++v) *(float4*)&ebuf[0][v * 256 + l * 4] = st[v];
#pragma unroll
    for (int v = 0; v < 4; ++v) st[v] = ebv[256 + v * 64 + l];

    float a = startT[j] + ebuf[0][j];      // t = 0
    unsigned bpw = 0;

    auto step = [&](float e, int t, int ph) {
        int x, y;
        plswap16(__float_as_int(a), x, y);
        int base = c16 ? x : y;
        int rot[16];
        ROTALL(rot, base);
        float s[16];
#pragma unroll
        for (int k = 0; k < 16; ++k) s[k] = __int_as_float(rot[k]) + Ti[k];

        // per-half exact max (tree shape can't change float max)
        float m0 = fmax3_(s[0], s[1], s[2]);
        float m1 = fmax3_(s[3], s[4], s[5]);
        float m2 = fmax3_(s[6], s[7], s[8]);
        float m3 = fmax3_(s[9], s[10], s[11]);
        float m4 = fmax3_(s[12], s[13], s[14]);
        float mv = fmaxf(fmax3_(m0, m1, m2), fmax3_(m3, m4, s[15]));

        // global max across halves
        int xm, ym;
        plswap32(__float_as_int(mv), xm, ym);
        float ov = __int_as_float(pick0 ? xm : ym);
        float gv = fmaxf(mv, ov);

        // match mask -> first (lowest) index achieving gv == jnp.argmax
        unsigned c0 = (s[0] == gv) ? Bk[0] : 0u,   c1 = (s[1] == gv) ? Bk[1] : 0u;
        unsigned c2 = (s[2] == gv) ? Bk[2] : 0u,   c3 = (s[3] == gv) ? Bk[3] : 0u;
        unsigned c4 = (s[4] == gv) ? Bk[4] : 0u,   c5 = (s[5] == gv) ? Bk[5] : 0u;
        unsigned c6 = (s[6] == gv) ? Bk[6] : 0u,   c7 = (s[7] == gv) ? Bk[7] : 0u;
        unsigned c8 = (s[8] == gv) ? Bk[8] : 0u,   c9 = (s[9] == gv) ? Bk[9] : 0u;
        unsigned c10 = (s[10] == gv) ? Bk[10] : 0u, c11 = (s[11] == gv) ? Bk[11] : 0u;
        unsigned c12 = (s[12] == gv) ? Bk[12] : 0u, c13 = (s[13] == gv) ? Bk[13] : 0u;
        unsigned c14 = (s[14] == gv) ? Bk[14] : 0u, c15 = (s[15] == gv) ? Bk[15] : 0u;
        unsigned t0_ = (c0 | c1 | c2);
        unsigned t1_ = (c3 | c4 | c5);
        unsigned t2_ = (c6 | c7 | c8);
        unsigned t3_ = (c9 | c10 | c11);
        unsigned t4_ = (c12 | c13 | c14);
        unsigned msk = (t0_ | t1_ | t2_) | (t3_ | t4_ | c15);

        int xk, yk;
        plswap32((int)msk, xk, yk);
        unsigned om = (unsigned)(pick0 ? xk : yk);
        unsigned full = msk | om;          // identical in both halves
        int wi = __builtin_ctz(full);      // min index among maximizers

        a = gv + e;

        bpw |= (unsigned)wi << (ph * 8);
        if (ph == 3) {
            int kk = t - 1;
            bp[((unsigned)(kk >> 2) * BB + b) * CC + j] = bpw;  // both halves: same addr+data
            bpw = 0;
        }
    };

    // block 0: steps t = 1..31
    {
        const float* buf = &ebuf[0][0];
#pragma unroll
        for (int u = 1; u < 32; ++u) step(buf[u * 32 + j], u, (u - 1) & 3);
    }
    // blocks m = 1..63: write staged regs, issue next loads, 32 steps
    for (int m = 1; m < 64; ++m) {
        float* buf = &ebuf[m & 1][0];
#pragma unroll
        for (int v = 0; v < 4; ++v) *(float4*)&buf[v * 256 + l * 4] = st[v];
        if (m < 63) {
#pragma unroll
            for (int v = 0; v < 4; ++v) st[v] = ebv[(m + 1) * 256 + v * 64 + l];
        }
        const int tb = m << 5;
#pragma unroll
        for (int u = 0; u < 32; ++u) step(buf[u * 32 + j], tb + u, (u + 3) & 3);
    }

    // slot 511: phases 0..2 real + IDENTITY byte (uniform 64-step walks in bt)
    bpw |= (unsigned)j << 24;
    bp[(511u * BB + b) * CC + j] = bpw;

    // final: best_score + last tag (tie -> lowest j)
    float v = a + endT[j];
    int idx = j;
#pragma unroll
    for (int d = 1; d <= 16; d <<= 1) {
        float ovv = __shfl_xor(v, d);
        int   oii = __shfl_xor(idx, d);
        bool c = (ovv > v) || (ovv == v && oii < idx);
        v = c ? ovv : v;
        idx = c ? oii : idx;
    }
    if (l == 0) {
        out[b] = v;
        out[BB + (long)b * SS + (SS - 1)] = (float)idx;
    }
}

// ---------------------------------------------------------------------------
// Backtrack as a function-composition scan over 32 chunks of 64 steps.
// UNCHANGED (passed; ~30-40 us total).
// ---------------------------------------------------------------------------
__global__ __launch_bounds__(64) void bt_compose(const unsigned* __restrict__ bp,
                                                 unsigned char* __restrict__ G) {
    const int l = threadIdx.x, j = l & 31, hh = l >> 5;
    const int b = blockIdx.x >> 4;
    const int k = ((blockIdx.x & 15) << 1) | hh;
    const int lanebase = l & 32;

    unsigned sr[16];
#pragma unroll
    for (int p = 0; p < 16; ++p) sr[p] = bp[((unsigned)(16 * k + p) * BB + b) * CC + j];

    int g = j;
#pragma unroll
    for (int rel = 63; rel >= 0; --rel) {
        unsigned dw = (unsigned)__builtin_amdgcn_ds_bpermute((g | lanebase) << 2,
                                                             (int)sr[rel >> 2]);
        g = (int)((dw >> ((rel & 3) * 8)) & 31u);
    }
    G[(b * 32 + k) * 32 + j] = (unsigned char)g;
}

__global__ __launch_bounds__(64) void bt_scan(const unsigned char* __restrict__ G,
                                              const float* __restrict__ out,
                                              int* __restrict__ tagB) {
    __shared__ unsigned char Gs[64 * 32 * 32];
    const int l = threadIdx.x;
    const float4* Gg = (const float4*)G;
    float4* Gls = (float4*)Gs;
#pragma unroll
    for (int i = 0; i < 64; ++i) Gls[l + i * 64] = Gg[l + i * 64];
    __syncthreads();

    const int b = l;
    int cur = (int)out[BB + (long)b * SS + (SS - 1)];
    for (int k = 31; k >= 0; --k) {
        cur = Gs[(b * 32 + k) * 32 + cur];
        tagB[b * 32 + k] = cur;
    }
}

__global__ __launch_bounds__(64) void bt_emit(const unsigned* __restrict__ bp,
                                              const int* __restrict__ tagB,
                                              float* __restrict__ out) {
    const int l = threadIdx.x;
    const int b = blockIdx.x >> 5;
    const int k = blockIdx.x & 31;

    unsigned sr[16];
#pragma unroll
    for (int p = 0; p < 16; ++p) sr[p] = bp[((unsigned)(16 * k + p) * BB + b) * CC + (l & 31)];

    int start = (k == 31) ? (int)out[BB + (long)b * SS + (SS - 1)]
                          : tagB[b * 32 + k + 1];
    int g = start, cap = start;
#pragma unroll
    for (int rel = 63; rel >= 0; --rel) {
        unsigned dw = (unsigned)__builtin_amdgcn_ds_bpermute((g | (l & 32)) << 2,
                                                             (int)sr[rel >> 2]);
        g = (int)((dw >> ((rel & 3) * 8)) & 31u);
        cap = (l == rel) ? g : cap;
    }
    out[BB + (long)b * SS + k * 64 + l] = (float)cap;
}

// ---------------------------------------------------------------------------
extern "C" void kernel_launch(void* const* d_in, const int* in_sizes, int n_in,
                              void* d_out, int out_size, void* d_ws, size_t ws_size,
                              hipStream_t stream) {
    const float* X      = (const float*)d_in[0];
    const float* W      = (const float*)d_in[1];
    const float* bias   = (const float*)d_in[2];
    const float* T      = (const float*)d_in[3];
    const float* startT = (const float*)d_in[4];
    const float* endT   = (const float*)d_in[5];
    float* out = (float*)d_out;

    float*    em = (float*)d_ws;                                        // 16 MB
    unsigned* bp = (unsigned*)((char*)d_ws + (size_t)BB * SS * CC * 4); // 4 MB
    unsigned char* G    = (unsigned char*)d_ws;                         // reuse em head
    int*           tagB = (int*)((char*)d_ws + 65536);

    emis_kernel<<<(BB * SS) / 64, 256, 0, stream>>>(X, W, bias, em);
    viterbi_fwd<<<BB, 64, 0, stream>>>(em, T, startT, endT, bp, out);
    bt_compose<<<BB * 16, 64, 0, stream>>>(bp, G);
    bt_scan<<<1, 64, 0, stream>>>(G, out, tagB);
    bt_emit<<<BB * 32, 64, 0, stream>>>(bp, tagB, out);
}

// Round 6
// 374.770 us; speedup vs baseline: 2.3727x; 1.6072x over previous
//
#include <hip/hip_runtime.h>

#define BB 64
#define SS 2048
#define FF 256
#define CC 32

typedef unsigned u32x2 __attribute__((ext_vector_type(2)));

// Two-result permlane swaps (builtin returns {vdst, vsrc} in distinct regs).
__device__ __forceinline__ void plswap16(int a_in, int& x, int& y) {
#if __has_builtin(__builtin_amdgcn_permlane16_swap)
    u32x2 r = __builtin_amdgcn_permlane16_swap((unsigned)a_in, (unsigned)a_in, false, false);
    x = (int)r[0]; y = (int)r[1];
#else
    int xx = a_in, yy;
    asm volatile("v_mov_b32 %0, %1" : "=v"(yy) : "v"(a_in));
    asm volatile("v_permlane16_swap_b32 %0, %1" : "+v"(xx), "+v"(yy));
    x = xx; y = yy;
#endif
}
__device__ __forceinline__ void plswap32(int a_in, int& x, int& y) {
#if __has_builtin(__builtin_amdgcn_permlane32_swap)
    u32x2 r = __builtin_amdgcn_permlane32_swap((unsigned)a_in, (unsigned)a_in, false, false);
    x = (int)r[0]; y = (int)r[1];
#else
    int xx = a_in, yy;
    asm volatile("v_mov_b32 %0, %1" : "=v"(yy) : "v"(a_in));
    asm volatile("v_permlane32_swap_b32 %0, %1" : "+v"(xx), "+v"(yy));
    x = xx; y = yy;
#endif
}

// Single-instruction DPP row-rotate (no old-value merge -> 1 v_mov_b32_dpp).
#if __has_builtin(__builtin_amdgcn_mov_dpp)
#define ROT1(d, s, K) d = __builtin_amdgcn_mov_dpp(s, 0x120 + K, 0xF, 0xF, false)
#else
#define ROT1(d, s, K) d = __builtin_amdgcn_update_dpp(s, s, 0x120 + K, 0xF, 0xF, false)
#endif
#define ROTALL(arr, s) \
    arr[0] = s;        \
    ROT1(arr[1], s, 1);  ROT1(arr[2], s, 2);  ROT1(arr[3], s, 3);  \
    ROT1(arr[4], s, 4);  ROT1(arr[5], s, 5);  ROT1(arr[6], s, 6);  \
    ROT1(arr[7], s, 7);  ROT1(arr[8], s, 8);  ROT1(arr[9], s, 9);  \
    ROT1(arr[10], s, 10); ROT1(arr[11], s, 11); ROT1(arr[12], s, 12); \
    ROT1(arr[13], s, 13); ROT1(arr[14], s, 14); ROT1(arr[15], s, 15)

__device__ __forceinline__ float fmax3_(float a, float b, float c) { return fmaxf(fmaxf(a, b), c); }

// ---------------------------------------------------------------------------
// Kernel 1: emissions GEMM — UNCHANGED (bit-exact; ~45 us).
// ---------------------------------------------------------------------------
__global__ __launch_bounds__(256) void emis_kernel(const float* __restrict__ X,
                                                   const float* __restrict__ W,
                                                   const float* __restrict__ bias,
                                                   float* __restrict__ em) {
    __shared__ __align__(16) float xs[64 * 260];
    __shared__ __align__(16) float wsh[32 * 260];
    const int tid = threadIdx.x;
    const long rowbase = (long)blockIdx.x * 64;

    const float4* Xg = (const float4*)(X + rowbase * FF);
#pragma unroll
    for (int i = 0; i < 16; ++i) {
        int idx = tid + i * 256;
        int r = idx >> 6, c4 = idx & 63;
        *(float4*)&xs[r * 260 + c4 * 4] = Xg[idx];
    }
    const float4* Wg = (const float4*)W;
#pragma unroll
    for (int i = 0; i < 8; ++i) {
        int idx = tid + i * 256;
        int r = idx >> 6, c4 = idx & 63;
        *(float4*)&wsh[r * 260 + c4 * 4] = Wg[idx];
    }
    __syncthreads();

    const int rp = tid >> 3;
    const int cg = (tid & 7) * 4;
    const int r0 = rp * 2, r1 = rp * 2 + 1;
    float acc0[4] = {0.f, 0.f, 0.f, 0.f};
    float acc1[4] = {0.f, 0.f, 0.f, 0.f};

#pragma unroll 4
    for (int k = 0; k < 256; k += 4) {
        float4 xa = *(const float4*)&xs[r0 * 260 + k];
        float4 xb = *(const float4*)&xs[r1 * 260 + k];
#pragma unroll
        for (int jj = 0; jj < 4; ++jj) {
            float4 w = *(const float4*)&wsh[(cg + jj) * 260 + k];
            acc0[jj] = fmaf(xa.x, w.x, acc0[jj]);
            acc0[jj] = fmaf(xa.y, w.y, acc0[jj]);
            acc0[jj] = fmaf(xa.z, w.z, acc0[jj]);
            acc0[jj] = fmaf(xa.w, w.w, acc0[jj]);
            acc1[jj] = fmaf(xb.x, w.x, acc1[jj]);
            acc1[jj] = fmaf(xb.y, w.y, acc1[jj]);
            acc1[jj] = fmaf(xb.z, w.z, acc1[jj]);
            acc1[jj] = fmaf(xb.w, w.w, acc1[jj]);
        }
    }
#pragma unroll
    for (int jj = 0; jj < 4; ++jj) {
        float bj = bias[cg + jj];
        em[(rowbase + r0) * CC + cg + jj] = acc0[jj] + bj;
        em[(rowbase + r1) * CC + cg + jj] = acc1[jj] + bj;
    }
}

// ---------------------------------------------------------------------------
// Kernel 2: forward alpha chain ONLY (argmax/bp moved to parallel bp_compose).
// 64 blocks x 1 wave. LDS double-buffered emission staging (proven r5).
// Stores alpha_t IN-PLACE over em[b][t][*] (e consumed from LDS before the
// overwrite; same wave, issue-ordered). ~46 VALU/step.
// ---------------------------------------------------------------------------
__global__ __launch_bounds__(64, 1) void viterbi_fwd_alpha(float* __restrict__ em,
                                                           const float* __restrict__ T,
                                                           const float* __restrict__ startT,
                                                           const float* __restrict__ endT,
                                                           float* __restrict__ out) {
    __shared__ float ebuf[2][1024];        // 2 x 32 steps x 32 states
    const int l = threadIdx.x;
    const int b = blockIdx.x;
    const int j = l & 31;
    const int h = l >> 5;

    // probe permlane16_swap orientation
    int p0, p1;
    plswap16(j, p0, p1);
    const bool c16 = (((p0 >> 4) & 1) == h);
    const int pm = c16 ? p0 : p1;
    int mk[16];
    ROTALL(mk, pm);
    // probe permlane32_swap orientation
    int q0, q1;
    plswap32(l, q0, q1);
    const bool pick0 = (q0 == (l ^ 32));

    float Ti[16];
#pragma unroll
    for (int k = 0; k < 16; ++k) Ti[k] = T[mk[k] * CC + j];

    float* eb = em + (long)b * SS * CC;
    const float4* ebv = (const float4*)eb;

    float4 st[4];
#pragma unroll
    for (int v = 0; v < 4; ++v) st[v] = ebv[v * 64 + l];
#pragma unroll
    for (int v = 0; v < 4; ++v) *(float4*)&ebuf[0][v * 256 + l * 4] = st[v];
#pragma unroll
    for (int v = 0; v < 4; ++v) st[v] = ebv[256 + v * 64 + l];

    float a = startT[j] + ebuf[0][j];      // alpha_0
    eb[j] = a;                             // store alpha_0 (dup lanes: same addr+data)

    auto step = [&](float e) {
        int x, y;
        plswap16(__float_as_int(a), x, y);
        int base = c16 ? x : y;
        int rot[16];
        ROTALL(rot, base);
        float s[16];
#pragma unroll
        for (int k = 0; k < 16; ++k) s[k] = __int_as_float(rot[k]) + Ti[k];

        float m0 = fmax3_(s[0], s[1], s[2]);
        float m1 = fmax3_(s[3], s[4], s[5]);
        float m2 = fmax3_(s[6], s[7], s[8]);
        float m3 = fmax3_(s[9], s[10], s[11]);
        float m4 = fmax3_(s[12], s[13], s[14]);
        float mv = fmaxf(fmax3_(m0, m1, m2), fmax3_(m3, m4, s[15]));

        int xm, ym;
        plswap32(__float_as_int(mv), xm, ym);
        float ov = __int_as_float(pick0 ? xm : ym);
        float gv = fmaxf(mv, ov);

        a = gv + e;
    };

    // block 0: steps t = 1..31
    {
        const float* buf = &ebuf[0][0];
#pragma unroll
        for (int u = 1; u < 32; ++u) {
            step(buf[u * 32 + j]);
            eb[u * 32 + j] = a;
        }
    }
    // blocks m = 1..63
    for (int m = 1; m < 64; ++m) {
        float* buf = &ebuf[m & 1][0];
#pragma unroll
        for (int v = 0; v < 4; ++v) *(float4*)&buf[v * 256 + l * 4] = st[v];
        if (m < 63) {
#pragma unroll
            for (int v = 0; v < 4; ++v) st[v] = ebv[(m + 1) * 256 + v * 64 + l];
        }
        const int tb = m << 5;
#pragma unroll
        for (int u = 0; u < 32; ++u) {
            step(buf[u * 32 + j]);
            eb[(tb + u) * 32 + j] = a;
        }
    }

    // final: best_score + last tag (tie -> lowest j)
    float v = a + endT[j];
    int idx = j;
#pragma unroll
    for (int d = 1; d <= 16; d <<= 1) {
        float ovv = __shfl_xor(v, d);
        int   oii = __shfl_xor(idx, d);
        bool c = (ovv > v) || (ovv == v && oii < idx);
        v = c ? ovv : v;
        idx = c ? oii : idx;
    }
    if (l == 0) {
        out[b] = v;
        out[BB + (long)b * SS + (SS - 1)] = (float)idx;
    }
}

// ---------------------------------------------------------------------------
// Kernel 3: bp_compose — recompute backpointers from stored alphas (exact r5
// semantics: same adds, same max tree, same ctz tie-break), pack 4/dword,
// store bp, and compose the chunk's 64 maps into G. Fully parallel:
// 64 batches x 32 chunks = 2048 waves.
// ---------------------------------------------------------------------------
__global__ __launch_bounds__(64, 2) void bp_compose(const float* __restrict__ alpha,
                                                    const float* __restrict__ T,
                                                    unsigned* __restrict__ bp,
                                                    unsigned char* __restrict__ G) {
    const int l = threadIdx.x;
    const int j = l & 31;
    const int h = l >> 5;
    const int b = blockIdx.x >> 5;
    const int k = blockIdx.x & 31;

    int p0, p1;
    plswap16(j, p0, p1);
    const bool c16 = (((p0 >> 4) & 1) == h);
    const int pm = c16 ? p0 : p1;
    int mk[16];
    ROTALL(mk, pm);
    int q0, q1;
    plswap32(l, q0, q1);
    const bool pick0 = (q0 == (l ^ 32));

    float Ti[16];
    unsigned Bk[16];
#pragma unroll
    for (int kk = 0; kk < 16; ++kk) {
        Ti[kk] = T[mk[kk] * CC + j];
        Bk[kk] = 1u << mk[kk];
    }

    const float* A = alpha + (long)b * SS * CC;
    const int kk0 = k << 6;                // first bp index of this chunk

    float aq[8];
#pragma unroll
    for (int v = 0; v < 8; ++v) aq[v] = A[(kk0 + v) * CC + j];

    unsigned sr[16];
#pragma unroll
    for (int p = 0; p < 16; ++p) sr[p] = 0u;

#pragma unroll
    for (int g8 = 0; g8 < 8; ++g8) {
#pragma unroll
        for (int v = 0; v < 8; ++v) {
            const int u = g8 * 8 + v;
            float av = aq[v];
            if (g8 < 7) aq[v] = A[(kk0 + (g8 + 1) * 8 + v) * CC + j];

            int x, y;
            plswap16(__float_as_int(av), x, y);
            int base = c16 ? x : y;
            int rot[16];
            ROTALL(rot, base);
            float s[16];
#pragma unroll
            for (int kk = 0; kk < 16; ++kk) s[kk] = __int_as_float(rot[kk]) + Ti[kk];

            float m0 = fmax3_(s[0], s[1], s[2]);
            float m1 = fmax3_(s[3], s[4], s[5]);
            float m2 = fmax3_(s[6], s[7], s[8]);
            float m3 = fmax3_(s[9], s[10], s[11]);
            float m4 = fmax3_(s[12], s[13], s[14]);
            float mv = fmaxf(fmax3_(m0, m1, m2), fmax3_(m3, m4, s[15]));

            int xm, ym;
            plswap32(__float_as_int(mv), xm, ym);
            float ov = __int_as_float(pick0 ? xm : ym);
            float gv = fmaxf(mv, ov);

            unsigned c0 = (s[0] == gv) ? Bk[0] : 0u,   c1 = (s[1] == gv) ? Bk[1] : 0u;
            unsigned c2 = (s[2] == gv) ? Bk[2] : 0u,   c3 = (s[3] == gv) ? Bk[3] : 0u;
            unsigned c4 = (s[4] == gv) ? Bk[4] : 0u,   c5 = (s[5] == gv) ? Bk[5] : 0u;
            unsigned c6 = (s[6] == gv) ? Bk[6] : 0u,   c7 = (s[7] == gv) ? Bk[7] : 0u;
            unsigned c8 = (s[8] == gv) ? Bk[8] : 0u,   c9 = (s[9] == gv) ? Bk[9] : 0u;
            unsigned c10 = (s[10] == gv) ? Bk[10] : 0u, c11 = (s[11] == gv) ? Bk[11] : 0u;
            unsigned c12 = (s[12] == gv) ? Bk[12] : 0u, c13 = (s[13] == gv) ? Bk[13] : 0u;
            unsigned c14 = (s[14] == gv) ? Bk[14] : 0u, c15 = (s[15] == gv) ? Bk[15] : 0u;
            unsigned msk = ((c0 | c1 | c2) | (c3 | c4 | c5)) |
                           ((c6 | c7 | c8) | (c9 | c10 | c11)) |
                           ((c12 | c13 | c14) | c15);

            int xk, yk;
            plswap32((int)msk, xk, yk);
            unsigned om = (unsigned)(pick0 ? xk : yk);
            int wi = __builtin_ctz(msk | om);

            if (u == 63) {                 // bp slot 2047 is IDENTITY filler
                if (kk0 + 63 == SS - 1) wi = j;
            }
            sr[u >> 2] |= (unsigned)wi << ((u & 3) * 8);
        }
    }

#pragma unroll
    for (int p = 0; p < 16; ++p)
        bp[((unsigned)(16 * k + p) * BB + b) * CC + j] = sr[p];

    int g = j;
#pragma unroll
    for (int rel = 63; rel >= 0; --rel) {
        unsigned dw = (unsigned)__builtin_amdgcn_ds_bpermute((g | (l & 32)) << 2,
                                                             (int)sr[rel >> 2]);
        g = (int)((dw >> ((rel & 3) * 8)) & 31u);
    }
    G[(b * 32 + k) * 32 + j] = (unsigned char)g;
}

// ---------------------------------------------------------------------------
// bt_scan / bt_emit — UNCHANGED (proven).
// ---------------------------------------------------------------------------
__global__ __launch_bounds__(64) void bt_scan(const unsigned char* __restrict__ G,
                                              const float* __restrict__ out,
                                              int* __restrict__ tagB) {
    __shared__ unsigned char Gs[64 * 32 * 32];
    const int l = threadIdx.x;
    const float4* Gg = (const float4*)G;
    float4* Gls = (float4*)Gs;
#pragma unroll
    for (int i = 0; i < 64; ++i) Gls[l + i * 64] = Gg[l + i * 64];
    __syncthreads();

    const int b = l;
    int cur = (int)out[BB + (long)b * SS + (SS - 1)];
    for (int k = 31; k >= 0; --k) {
        cur = Gs[(b * 32 + k) * 32 + cur];
        tagB[b * 32 + k] = cur;
    }
}

__global__ __launch_bounds__(64) void bt_emit(const unsigned* __restrict__ bp,
                                              const int* __restrict__ tagB,
                                              float* __restrict__ out) {
    const int l = threadIdx.x;
    const int b = blockIdx.x >> 5;
    const int k = blockIdx.x & 31;

    unsigned sr[16];
#pragma unroll
    for (int p = 0; p < 16; ++p) sr[p] = bp[((unsigned)(16 * k + p) * BB + b) * CC + (l & 31)];

    int start = (k == 31) ? (int)out[BB + (long)b * SS + (SS - 1)]
                          : tagB[b * 32 + k + 1];
    int g = start, cap = start;
#pragma unroll
    for (int rel = 63; rel >= 0; --rel) {
        unsigned dw = (unsigned)__builtin_amdgcn_ds_bpermute((g | (l & 32)) << 2,
                                                             (int)sr[rel >> 2]);
        g = (int)((dw >> ((rel & 3) * 8)) & 31u);
        cap = (l == rel) ? g : cap;
    }
    out[BB + (long)b * SS + k * 64 + l] = (float)cap;
}

// ---------------------------------------------------------------------------
extern "C" void kernel_launch(void* const* d_in, const int* in_sizes, int n_in,
                              void* d_out, int out_size, void* d_ws, size_t ws_size,
                              hipStream_t stream) {
    const float* X      = (const float*)d_in[0];
    const float* W      = (const float*)d_in[1];
    const float* bias   = (const float*)d_in[2];
    const float* T      = (const float*)d_in[3];
    const float* startT = (const float*)d_in[4];
    const float* endT   = (const float*)d_in[5];
    float* out = (float*)d_out;

    float*    em = (float*)d_ws;                                        // 16 MB (e -> alpha in-place)
    unsigned* bp = (unsigned*)((char*)d_ws + (size_t)BB * SS * CC * 4); // 4 MB @ 16 MB
    unsigned char* G    = (unsigned char*)d_ws + (20u << 20);           // 64 KB @ 20 MB
    int*           tagB = (int*)((char*)d_ws + (20u << 20) + 65536);    // 8 KB

    emis_kernel<<<(BB * SS) / 64, 256, 0, stream>>>(X, W, bias, em);
    viterbi_fwd_alpha<<<BB, 64, 0, stream>>>(em, T, startT, endT, out);
    bp_compose<<<BB * 32, 64, 0, stream>>>(em, T, bp, G);
    bt_scan<<<1, 64, 0, stream>>>(G, out, tagB);
    bt_emit<<<BB * 32, 64, 0, stream>>>(bp, tagB, out);
}